// Round 14
// baseline (129.956 us; speedup 1.0000x reference)
//
#include <hip/hip_runtime.h>

#define NPTS 131072
#define DIM  128
#define KC   1024

using half8 = __attribute__((ext_vector_type(8))) _Float16;
using f32x4 = __attribute__((ext_vector_type(4))) float;

static __device__ __forceinline__ unsigned umax_(unsigned a, unsigned b){ return a > b ? a : b; }
static __device__ __forceinline__ unsigned med3u(unsigned a, unsigned b, unsigned c){
    unsigned d;
    asm("v_med3_u32 %0, %1, %2, %3" : "=v"(d) : "v"(a), "v"(b), "v"(c));
    return d;
}

// ws layout (bytes):
//   [0, 262144)        f16 codebook image, 16 chunks x 16KB, FRAGMENT-MAJOR:
//                      element (code, k), code=(ch*64 + ct*16 + c), k=(kc*32 + g*8 + j)
//                      at ch*16384 + ct*4096 + kc*1024 + g*256 + c*16 + j*2
//   [262144, 266240)   eeW[1024] = 0.5*||e||^2 - 512   (chunk-contiguous)
//   [266240, 270336)   bsum[1024]

// ---- prep: fragment-major f16 image + eeW, one wave per code ----
__global__ void vq_prep(const float* __restrict__ emb, unsigned short* __restrict__ wsE,
                        float* __restrict__ eeW) {
    int lane = threadIdx.x & 63, wv = threadIdx.x >> 6;
    int code = blockIdx.x * 4 + wv;                 // 256 blocks x 4 waves = 1024 codes
    const float* e = emb + (size_t)code * DIM;
    float a = e[lane], b = e[lane + 64];            // k = lane, k = lane+64

    int chunk = code >> 6, r = code & 63;
    int ct = r >> 4, c = r & 15;
    int kc = lane >> 5, g = (lane >> 3) & 3, j = lane & 7;
    size_t off = (size_t)chunk * 16384 + (size_t)(ct * 4096 + kc * 1024 + g * 256 + c * 16 + j * 2);
    _Float16 ha = (_Float16)a, hb = (_Float16)b;
    wsE[off >> 1]          = __builtin_bit_cast(unsigned short, ha);
    wsE[(off + 2048) >> 1] = __builtin_bit_cast(unsigned short, hb);

    float v = a * a + b * b;
    #pragma unroll
    for (int o = 32; o > 0; o >>= 1) v += __shfl_down(v, o);
    if (lane == 0) eeW[code] = 0.5f * v - 512.0f;
}

// ---- fused pass: 4 waves x 32 rows (B-frag shared by 2 A-tiles), counted-vmcnt 3-buf ----
__global__ __launch_bounds__(256, 2) void vq_mfma(const float* __restrict__ x,
                                                  const float* __restrict__ emb,
                                                  const unsigned short* __restrict__ wsE,
                                                  const float* __restrict__ eeW,
                                                  float* __restrict__ out,
                                                  float* __restrict__ bsum) {
    __shared__ __attribute__((aligned(128))) char lds[3][16640];
    __shared__ int   lbest[128];
    __shared__ float red[4];
    const int tid  = threadIdx.x;
    const int lane = tid & 63, wv = tid >> 6;       // 4 waves
    const int g    = lane >> 4, c = lane & 15;
    const int blockbase = blockIdx.x * 128;

    // A fragments: x row (blockbase + wv*32 + rt*16 + c), k = kc*32 + g*8 + j
    half8 ah[2][4];
    #pragma unroll
    for (int rt = 0; rt < 2; ++rt) {
        const float* xr = x + (size_t)(blockbase + wv * 32 + rt * 16 + c) * DIM;
        #pragma unroll
        for (int kc = 0; kc < 4; ++kc) {
            const float4* p = reinterpret_cast<const float4*>(xr + kc * 32 + g * 8);
            float4 v0 = p[0], v1 = p[1];
            half8 hh;
            hh[0] = (_Float16)v0.x; hh[1] = (_Float16)v0.y;
            hh[2] = (_Float16)v0.z; hh[3] = (_Float16)v0.w;
            hh[4] = (_Float16)v1.x; hh[5] = (_Float16)v1.y;
            hh[6] = (_Float16)v1.z; hh[7] = (_Float16)v1.w;
            ah[rt][kc] = hh;
        }
    }

    unsigned m1[8], m2[8], m3[8];          // [rt*4+q] packed keys, descending
    #pragma unroll
    for (int i = 0; i < 8; ++i) { m1[i] = 0u; m2[i] = 0u; m3[i] = 0u; }

    // 5 vm-ops/wave: 4x b128 slice + duplicated 256B eeW copy (identical data, benign).
    #define STAGE(BUF, CH)                                                                   \
        do {                                                                                 \
            const char* src_ = (const char*)wsE + (size_t)(CH) * 16384 + (size_t)wv * 4096;  \
            char* dst_ = &lds[(BUF)][0] + wv * 4096;                                         \
            _Pragma("unroll")                                                                \
            for (int it = 0; it < 4; ++it) {                                                 \
                __builtin_amdgcn_global_load_lds(                                            \
                    (const __attribute__((address_space(1))) void*)(src_ + it * 1024 + lane * 16), \
                    (__attribute__((address_space(3))) void*)(dst_ + it * 1024),             \
                    16, 0, 0);                                                               \
            }                                                                                \
            __builtin_amdgcn_global_load_lds(                                                \
                (const __attribute__((address_space(1))) void*)(eeW + (size_t)(CH) * 64 + lane), \
                (__attribute__((address_space(3))) void*)(&lds[(BUF)][0] + 16384),           \
                4, 0, 0);                                                                    \
        } while (0)

    STAGE(0, 0);
    STAGE(1, 1);

    #pragma unroll
    for (int ch = 0; ch < 16; ++ch) {
        // stage(ch) complete; stage(ch+1)'s 5 ops may stay in flight across the barrier
        if (ch < 15) { asm volatile("s_waitcnt vmcnt(5)" ::: "memory"); }
        else         { asm volatile("s_waitcnt vmcnt(0)" ::: "memory"); }
        __builtin_amdgcn_sched_barrier(0);
        __builtin_amdgcn_s_barrier();          // raw: no vmcnt drain
        __builtin_amdgcn_sched_barrier(0);
        if (ch + 2 < 16) STAGE((ch + 2) % 3, ch + 2);   // overwrites buf[(ch-1)%3], released at barrier

        const char* L  = &lds[ch % 3][0];
        const char* Lf = L + (size_t)(lane << 4);       // this lane's fragment base

        #pragma unroll
        for (int ct = 0; ct < 4; ++ct) {
            const float eec = *reinterpret_cast<const float*>(L + 16384 + ((ct * 16 + c) << 2));
            half8 b0 = *reinterpret_cast<const half8*>(Lf + (ct * 4096 + 0 * 1024));
            half8 b1 = *reinterpret_cast<const half8*>(Lf + (ct * 4096 + 1 * 1024));
            half8 b2 = *reinterpret_cast<const half8*>(Lf + (ct * 4096 + 2 * 1024));
            half8 b3 = *reinterpret_cast<const half8*>(Lf + (ct * 4096 + 3 * 1024));
            f32x4 acc0 = {-eec, -eec, -eec, -eec};   // fold -eeW into C-in (one code/column)
            f32x4 acc1 = {-eec, -eec, -eec, -eec};
            acc0 = __builtin_amdgcn_mfma_f32_16x16x32_f16(ah[0][0], b0, acc0, 0, 0, 0);
            acc1 = __builtin_amdgcn_mfma_f32_16x16x32_f16(ah[1][0], b0, acc1, 0, 0, 0);
            acc0 = __builtin_amdgcn_mfma_f32_16x16x32_f16(ah[0][1], b1, acc0, 0, 0, 0);
            acc1 = __builtin_amdgcn_mfma_f32_16x16x32_f16(ah[1][1], b1, acc1, 0, 0, 0);
            acc0 = __builtin_amdgcn_mfma_f32_16x16x32_f16(ah[0][2], b2, acc0, 0, 0, 0);
            acc1 = __builtin_amdgcn_mfma_f32_16x16x32_f16(ah[1][2], b2, acc1, 0, 0, 0);
            acc0 = __builtin_amdgcn_mfma_f32_16x16x32_f16(ah[0][3], b3, acc0, 0, 0, 0);
            acc1 = __builtin_amdgcn_mfma_f32_16x16x32_f16(ah[1][3], b3, acc1, 0, 0, 0);

            const unsigned codeC = (unsigned)(1023 - (ch * 64 + ct * 16 + c));
            #pragma unroll
            for (int q = 0; q < 4; ++q) {
                #pragma unroll
                for (int rt = 0; rt < 2; ++rt) {
                    float sp = (rt ? acc1[q] : acc0[q]);          // > 0 (bias +512)
                    unsigned u   = __builtin_bit_cast(unsigned, sp);
                    unsigned key = (u & 0xFFFFFC00u) | codeC;     // v_and_or
                    const int i = rt * 4 + q;
                    m3[i] = med3u(m2[i], m3[i], key);             // uses old m2
                    m2[i] = med3u(m1[i], m2[i], key);
                    m1[i] = umax_(m1[i], key);
                }
            }
        }
    }

    // merge top-3 across the 16 code-lanes of each g-group; stash in LDS
    #pragma unroll
    for (int rt = 0; rt < 2; ++rt) {
        #pragma unroll
        for (int q = 0; q < 4; ++q) {
            const int i = rt * 4 + q;
            unsigned a1 = m1[i], a2 = m2[i], a3 = m3[i];
            #pragma unroll
            for (int mk = 1; mk < 16; mk <<= 1) {
                unsigned b1 = (unsigned)__shfl_xor((int)a1, mk, 64);
                unsigned b2 = (unsigned)__shfl_xor((int)a2, mk, 64);
                unsigned b3 = (unsigned)__shfl_xor((int)a3, mk, 64);
                unsigned c1 = umax_(a1, b1), t1 = (a1 < b1 ? a1 : b1);
                unsigned u1 = umax_(a2, b2), u2 = (a2 < b2 ? a2 : b2);
                unsigned c2 = umax_(t1, u1), t2 = (t1 < u1 ? t1 : u1);
                unsigned c3 = umax_(umax_(t2, u2), umax_(a3, b3));
                a1 = c1; a2 = c2; a3 = c3;
            }
            if (c == 0) {
                int lr = wv * 32 + rt * 16 + g * 4 + q;
                int i1 = 1023 - (int)(a1 & 1023u);
                int i2 = 1023 - (int)(a2 & 1023u);
                int i3 = 1023 - (int)(a3 & 1023u);
                lbest[lr] = i1 | (i2 << 10) | (i3 << 20);
            }
        }
    }
    __syncthreads();

    // ---- epilogue: exact fp32 over 3 candidates (x streamed), 2 thr/row, gather, loss ----
    {
        const int lrow = tid >> 1, hf = tid & 1;
        const int grow = blockbase + lrow;
        const int pk = lbest[lrow];
        const int ia = pk & 1023, ib = (pk >> 10) & 1023, ic = (pk >> 20) & 1023;

        const float4* xv4 = reinterpret_cast<const float4*>(x + (size_t)grow * DIM + hf * 64);
        const float4* ea = reinterpret_cast<const float4*>(emb + (size_t)ia * DIM + hf * 64);
        const float4* eb = reinterpret_cast<const float4*>(emb + (size_t)ib * DIM + hf * 64);
        const float4* ec = reinterpret_cast<const float4*>(emb + (size_t)ic * DIM + hf * 64);
        float da = 0.f, db = 0.f, dc = 0.f;
        #pragma unroll 4
        for (int i = 0; i < 16; ++i) {
            float4 xx = xv4[i];
            float4 va = ea[i], vb = eb[i], vc = ec[i];
            float ax = va.x - xx.x, ay = va.y - xx.y, az = va.z - xx.z, aw = va.w - xx.w;
            float bx = vb.x - xx.x, by = vb.y - xx.y, bz = vb.z - xx.z, bw = vb.w - xx.w;
            float cx = vc.x - xx.x, cy = vc.y - xx.y, cz = vc.z - xx.z, cw = vc.w - xx.w;
            da += ax * ax + ay * ay + az * az + aw * aw;
            db += bx * bx + by * by + bz * bz + bw * bw;
            dc += cx * cx + cy * cy + cz * cz + cw * cw;
        }
        da += __shfl_xor(da, 1, 64);
        db += __shfl_xor(db, 1, 64);
        dc += __shfl_xor(dc, 1, 64);

        int idx = ia; float dm = da;
        if (db < dm || (db == dm && ib < idx)) { dm = db; idx = ib; }
        if (dc < dm || (dc == dm && ic < idx)) { dm = dc; idx = ic; }

        if (hf == 0) out[grow] = (float)idx;

        const float4* q4 = reinterpret_cast<const float4*>(emb + (size_t)idx * DIM + hf * 64);
        float4* oq = reinterpret_cast<float4*>(out + (size_t)NPTS + (size_t)grow * DIM + hf * 64);
        #pragma unroll
        for (int i = 0; i < 16; ++i) oq[i] = q4[i];

        float lsum = (hf == 0) ? dm : 0.f;   // dm = exact ||x-q||^2 for the chosen code
        #pragma unroll
        for (int o = 32; o > 0; o >>= 1) lsum += __shfl_down(lsum, o);
        if (lane == 0) red[wv] = lsum;
        __syncthreads();
        if (tid == 0) bsum[blockIdx.x] = (red[0] + red[1]) + (red[2] + red[3]);
    }
    #undef STAGE
}

__global__ void vq_finalize(const float* __restrict__ bsum, float* __restrict__ out) {
    __shared__ float red[16];
    int t = threadIdx.x;  // 1024 threads
    float v = bsum[t];
    #pragma unroll
    for (int o = 32; o > 0; o >>= 1) v += __shfl_down(v, o);
    if ((t & 63) == 0) red[t >> 6] = v;
    __syncthreads();
    if (t == 0) {
        float s = 0.f;
        #pragma unroll
        for (int i = 0; i < 16; ++i) s += red[i];
        out[(size_t)NPTS + (size_t)NPTS * DIM] = 1.25f * s / 16777216.0f;
    }
}

// ---- fallback (round-2 proven path; eeW bias is argmax-safe) ----
__global__ void vq_ee(const float* __restrict__ emb, float* __restrict__ eeW) {
    int gid  = blockIdx.x * blockDim.x + threadIdx.x;
    int w    = gid >> 6;
    int lane = threadIdx.x & 63;
    const float* e = emb + (size_t)w * DIM;
    float a = e[lane];
    float b = e[lane + 64];
    float v = a * a + b * b;
    #pragma unroll
    for (int o = 32; o > 0; o >>= 1) v += __shfl_down(v, o);
    if (lane == 0) eeW[w] = 0.5f * v - 512.0f;
}

__global__ __launch_bounds__(256, 1) void vq_main(const float* __restrict__ x,
                                                  const float* __restrict__ emb,
                                                  const float* __restrict__ eeW,
                                                  float* __restrict__ out,
                                                  float* __restrict__ bsum) {
    const int p = blockIdx.x * 256 + threadIdx.x;
    float4 xr[32];
    const float4* xv = reinterpret_cast<const float4*>(x + (size_t)p * DIM);
    #pragma unroll
    for (int i = 0; i < 32; ++i) xr[i] = xv[i];
    float bestv = -3.4e38f; int bi = 0;
    for (int k = 0; k < KC; ++k) {
        const int ku = __builtin_amdgcn_readfirstlane(k);
        const float4* e4 = reinterpret_cast<const float4*>(emb + (size_t)ku * DIM);
        float a0 = 0.f, a1 = 0.f, a2 = 0.f, a3 = 0.f;
        #pragma unroll
        for (int i = 0; i < 32; ++i) {
            float4 ev = e4[i];
            a0 = fmaf(xr[i].x, ev.x, a0);
            a1 = fmaf(xr[i].y, ev.y, a1);
            a2 = fmaf(xr[i].z, ev.z, a2);
            a3 = fmaf(xr[i].w, ev.w, a3);
        }
        float s = ((a0 + a1) + (a2 + a3)) - eeW[ku];
        if (s > bestv) { bestv = s; bi = k; }
    }
    out[p] = (float)bi;
    const float4* q4 = reinterpret_cast<const float4*>(emb + (size_t)bi * DIM);
    float4* oq = reinterpret_cast<float4*>(out + (size_t)NPTS + (size_t)p * DIM);
    float lsum = 0.f;
    #pragma unroll
    for (int i = 0; i < 32; ++i) {
        float4 qv = q4[i];
        oq[i] = qv;
        float dx = qv.x - xr[i].x;
        float dy = qv.y - xr[i].y;
        float dz = qv.z - xr[i].z;
        float dw = qv.w - xr[i].w;
        lsum += dx * dx + dy * dy + dz * dz + dw * dw;
    }
    __shared__ float red[4];
    #pragma unroll
    for (int o = 32; o > 0; o >>= 1) lsum += __shfl_down(lsum, o);
    int lane = threadIdx.x & 63, wvl = threadIdx.x >> 6;
    if (lane == 0) red[wvl] = lsum;
    __syncthreads();
    if (threadIdx.x == 0) bsum[blockIdx.x] = (red[0] + red[1]) + (red[2] + red[3]);
}

__global__ void vq_finalize512(const float* __restrict__ bsum, float* __restrict__ out) {
    __shared__ float red[8];
    int t = threadIdx.x;  // 512 threads
    float v = bsum[t];
    #pragma unroll
    for (int o = 32; o > 0; o >>= 1) v += __shfl_down(v, o);
    if ((t & 63) == 0) red[t >> 6] = v;
    __syncthreads();
    if (t == 0) {
        float s = 0.f;
        #pragma unroll
        for (int i = 0; i < 8; ++i) s += red[i];
        out[(size_t)NPTS + (size_t)NPTS * DIM] = 1.25f * s / 16777216.0f;
    }
}

extern "C" void kernel_launch(void* const* d_in, const int* in_sizes, int n_in,
                              void* d_out, int out_size, void* d_ws, size_t ws_size,
                              hipStream_t stream) {
    const float* x   = (const float*)d_in[0];
    const float* emb = (const float*)d_in[1];
    float* out = (float*)d_out;
    char*  ws  = (char*)d_ws;

    if (ws_size >= 270336) {
        unsigned short* wsE = (unsigned short*)ws;           // 256 KB f16 image
        float* eeW  = (float*)(ws + 262144);                 // 4 KB
        float* bsum = (float*)(ws + 266240);                 // 4 KB
        vq_prep<<<256, 256, 0, stream>>>(emb, wsE, eeW);
        vq_mfma<<<1024, 256, 0, stream>>>(x, emb, wsE, eeW, out, bsum);
        vq_finalize<<<1, 1024, 0, stream>>>(bsum, out);
    } else {
        float* eeW  = (float*)ws;
        float* bsum = (float*)ws + 1024;
        vq_ee<<<256, 256, 0, stream>>>(emb, eeW);
        vq_main<<<512, 256, 0, stream>>>(x, emb, eeW, out, bsum);
        vq_finalize512<<<1, 512, 0, stream>>>(bsum, out);
    }
}

// Round 15
// 114.685 us; speedup vs baseline: 1.1332x; 1.1332x over previous
//
#include <hip/hip_runtime.h>

#define NPTS 131072
#define DIM  128
#define KC   1024

using half8 = __attribute__((ext_vector_type(8))) _Float16;
using f32x4 = __attribute__((ext_vector_type(4))) float;

static __device__ __forceinline__ unsigned umax_(unsigned a, unsigned b){ return a > b ? a : b; }
static __device__ __forceinline__ unsigned med3u(unsigned a, unsigned b, unsigned c){
    unsigned d;
    asm("v_med3_u32 %0, %1, %2, %3" : "=v"(d) : "v"(a), "v"(b), "v"(c));
    return d;
}

// ws layout (bytes):
//   [0, 262144)        f16 codebook image, 16 chunks x 16KB, FRAGMENT-MAJOR:
//                      element (code, k), code=(ch*64 + ct*16 + c), k=(kc*32 + g*8 + j)
//                      at ch*16384 + ct*4096 + kc*1024 + g*256 + c*16 + j*2
//   [262144, 266240)   eeW[1024] = 0.5*||e||^2 - 512   (chunk-contiguous)
//   [266240, 268288)   bsum[512]

// ---- prep: fragment-major f16 image + eeW, one wave per code ----
__global__ void vq_prep(const float* __restrict__ emb, unsigned short* __restrict__ wsE,
                        float* __restrict__ eeW) {
    int lane = threadIdx.x & 63, wv = threadIdx.x >> 6;
    int code = blockIdx.x * 4 + wv;                 // 256 blocks x 4 waves = 1024 codes
    const float* e = emb + (size_t)code * DIM;
    float a = e[lane], b = e[lane + 64];            // k = lane, k = lane+64

    int chunk = code >> 6, r = code & 63;
    int ct = r >> 4, c = r & 15;
    int kc = lane >> 5, g = (lane >> 3) & 3, j = lane & 7;
    size_t off = (size_t)chunk * 16384 + (size_t)(ct * 4096 + kc * 1024 + g * 256 + c * 16 + j * 2);
    _Float16 ha = (_Float16)a, hb = (_Float16)b;
    wsE[off >> 1]          = __builtin_bit_cast(unsigned short, ha);
    wsE[(off + 2048) >> 1] = __builtin_bit_cast(unsigned short, hb);

    float v = a * a + b * b;
    #pragma unroll
    for (int o = 32; o > 0; o >>= 1) v += __shfl_down(v, o);
    if (lane == 0) eeW[code] = 0.5f * v - 512.0f;
}

// ---- fused pass: 8 waves x 32 rows (B-frag shared by 2 A-tiles), counted-vmcnt 3-buf ----
__global__ __launch_bounds__(512, 1) void vq_mfma(const float* __restrict__ x,
                                                  const float* __restrict__ emb,
                                                  const unsigned short* __restrict__ wsE,
                                                  const float* __restrict__ eeW,
                                                  float* __restrict__ out,
                                                  float* __restrict__ bsum) {
    __shared__ __attribute__((aligned(128))) char lds[3][16640];
    __shared__ int   lbest[256];
    __shared__ float red[8];
    const int tid  = threadIdx.x;
    const int lane = tid & 63, wv = tid >> 6;       // 8 waves
    const int g    = lane >> 4, c = lane & 15;
    const int blockbase = blockIdx.x * 256;

    // A fragments: x row (blockbase + wv*32 + rt*16 + c), k = kc*32 + g*8 + j
    half8 ah[2][4];
    #pragma unroll
    for (int rt = 0; rt < 2; ++rt) {
        const float* xr = x + (size_t)(blockbase + wv * 32 + rt * 16 + c) * DIM;
        #pragma unroll
        for (int kc = 0; kc < 4; ++kc) {
            const float4* p = reinterpret_cast<const float4*>(xr + kc * 32 + g * 8);
            float4 v0 = p[0], v1 = p[1];
            half8 hh;
            hh[0] = (_Float16)v0.x; hh[1] = (_Float16)v0.y;
            hh[2] = (_Float16)v0.z; hh[3] = (_Float16)v0.w;
            hh[4] = (_Float16)v1.x; hh[5] = (_Float16)v1.y;
            hh[6] = (_Float16)v1.z; hh[7] = (_Float16)v1.w;
            ah[rt][kc] = hh;
        }
    }

    unsigned m1[8], m2[8], m3[8];          // [rt*4+q] packed keys, descending
    #pragma unroll
    for (int i = 0; i < 8; ++i) { m1[i] = 0u; m2[i] = 0u; m3[i] = 0u; }

    // 3 vm-ops/wave: 2x b128 slice + duplicated 256B eeW copy (identical data, benign).
    #define STAGE(BUF, CH)                                                                   \
        do {                                                                                 \
            const char* src_ = (const char*)wsE + (size_t)(CH) * 16384 + (size_t)wv * 2048;  \
            char* dst_ = &lds[(BUF)][0] + wv * 2048;                                         \
            _Pragma("unroll")                                                                \
            for (int it = 0; it < 2; ++it) {                                                 \
                __builtin_amdgcn_global_load_lds(                                            \
                    (const __attribute__((address_space(1))) void*)(src_ + it * 1024 + lane * 16), \
                    (__attribute__((address_space(3))) void*)(dst_ + it * 1024),             \
                    16, 0, 0);                                                               \
            }                                                                                \
            __builtin_amdgcn_global_load_lds(                                                \
                (const __attribute__((address_space(1))) void*)(eeW + (size_t)(CH) * 64 + lane), \
                (__attribute__((address_space(3))) void*)(&lds[(BUF)][0] + 16384),           \
                4, 0, 0);                                                                    \
        } while (0)

    STAGE(0, 0);
    STAGE(1, 1);

    #pragma unroll
    for (int ch = 0; ch < 16; ++ch) {
        // stage(ch) complete; stage(ch+1)'s 3 ops may stay in flight across the barrier
        if (ch < 15) { asm volatile("s_waitcnt vmcnt(3)" ::: "memory"); }
        else         { asm volatile("s_waitcnt vmcnt(0)" ::: "memory"); }
        __builtin_amdgcn_sched_barrier(0);
        __builtin_amdgcn_s_barrier();          // raw: no vmcnt drain
        __builtin_amdgcn_sched_barrier(0);
        if (ch + 2 < 16) STAGE((ch + 2) % 3, ch + 2);   // overwrites buf[(ch-1)%3], released at barrier

        const char* L  = &lds[ch % 3][0];
        const char* Lf = L + (size_t)(lane << 4);       // this lane's fragment base

        #pragma unroll
        for (int ct = 0; ct < 4; ++ct) {
            const float eec = *reinterpret_cast<const float*>(L + 16384 + ((ct * 16 + c) << 2));
            half8 b0 = *reinterpret_cast<const half8*>(Lf + (ct * 4096 + 0 * 1024));
            half8 b1 = *reinterpret_cast<const half8*>(Lf + (ct * 4096 + 1 * 1024));
            half8 b2 = *reinterpret_cast<const half8*>(Lf + (ct * 4096 + 2 * 1024));
            half8 b3 = *reinterpret_cast<const half8*>(Lf + (ct * 4096 + 3 * 1024));
            f32x4 acc0 = {-eec, -eec, -eec, -eec};   // fold -eeW into C-in (one code/column)
            f32x4 acc1 = {-eec, -eec, -eec, -eec};
            acc0 = __builtin_amdgcn_mfma_f32_16x16x32_f16(ah[0][0], b0, acc0, 0, 0, 0);
            acc1 = __builtin_amdgcn_mfma_f32_16x16x32_f16(ah[1][0], b0, acc1, 0, 0, 0);
            acc0 = __builtin_amdgcn_mfma_f32_16x16x32_f16(ah[0][1], b1, acc0, 0, 0, 0);
            acc1 = __builtin_amdgcn_mfma_f32_16x16x32_f16(ah[1][1], b1, acc1, 0, 0, 0);
            acc0 = __builtin_amdgcn_mfma_f32_16x16x32_f16(ah[0][2], b2, acc0, 0, 0, 0);
            acc1 = __builtin_amdgcn_mfma_f32_16x16x32_f16(ah[1][2], b2, acc1, 0, 0, 0);
            acc0 = __builtin_amdgcn_mfma_f32_16x16x32_f16(ah[0][3], b3, acc0, 0, 0, 0);
            acc1 = __builtin_amdgcn_mfma_f32_16x16x32_f16(ah[1][3], b3, acc1, 0, 0, 0);

            const unsigned codeC = (unsigned)(1023 - (ch * 64 + ct * 16 + c));
            #pragma unroll
            for (int q = 0; q < 4; ++q) {
                #pragma unroll
                for (int rt = 0; rt < 2; ++rt) {
                    float sp = (rt ? acc1[q] : acc0[q]);          // > 0 (bias +512)
                    unsigned u   = __builtin_bit_cast(unsigned, sp);
                    unsigned key = (u & 0xFFFFFC00u) | codeC;     // v_and_or
                    const int i = rt * 4 + q;
                    m3[i] = med3u(m2[i], m3[i], key);             // uses old m2
                    m2[i] = med3u(m1[i], m2[i], key);
                    m1[i] = umax_(m1[i], key);
                }
            }
        }
    }

    // merge top-3 across the 16 code-lanes of each g-group; stash in LDS
    #pragma unroll
    for (int rt = 0; rt < 2; ++rt) {
        #pragma unroll
        for (int q = 0; q < 4; ++q) {
            const int i = rt * 4 + q;
            unsigned a1 = m1[i], a2 = m2[i], a3 = m3[i];
            #pragma unroll
            for (int mk = 1; mk < 16; mk <<= 1) {
                unsigned b1 = (unsigned)__shfl_xor((int)a1, mk, 64);
                unsigned b2 = (unsigned)__shfl_xor((int)a2, mk, 64);
                unsigned b3 = (unsigned)__shfl_xor((int)a3, mk, 64);
                unsigned c1 = umax_(a1, b1), t1 = (a1 < b1 ? a1 : b1);
                unsigned u1 = umax_(a2, b2), u2 = (a2 < b2 ? a2 : b2);
                unsigned c2 = umax_(t1, u1), t2 = (t1 < u1 ? t1 : u1);
                unsigned c3 = umax_(umax_(t2, u2), umax_(a3, b3));
                a1 = c1; a2 = c2; a3 = c3;
            }
            if (c == 0) {
                int lr = wv * 32 + rt * 16 + g * 4 + q;
                int i1 = 1023 - (int)(a1 & 1023u);
                int i2 = 1023 - (int)(a2 & 1023u);
                int i3 = 1023 - (int)(a3 & 1023u);
                lbest[lr] = i1 | (i2 << 10) | (i3 << 20);
            }
        }
    }
    __syncthreads();

    // ---- epilogue (r7-proven clean shape): xr preloaded, fully unrolled, 2 thr/row ----
    {
        const int lrow = tid >> 1, hf = tid & 1;        // 256 rows x 2 half-threads
        const int grow = blockbase + lrow;
        const int pk = lbest[lrow];
        const int ia = pk & 1023, ib = (pk >> 10) & 1023, ic = (pk >> 20) & 1023;

        const float4* xv4 = reinterpret_cast<const float4*>(x + (size_t)grow * DIM + hf * 64);
        float4 xr[16];
        #pragma unroll
        for (int i = 0; i < 16; ++i) xr[i] = xv4[i];

        const float4* ea = reinterpret_cast<const float4*>(emb + (size_t)ia * DIM + hf * 64);
        const float4* eb = reinterpret_cast<const float4*>(emb + (size_t)ib * DIM + hf * 64);
        const float4* ec = reinterpret_cast<const float4*>(emb + (size_t)ic * DIM + hf * 64);
        float da = 0.f, db = 0.f, dc = 0.f;
        #pragma unroll
        for (int i = 0; i < 16; ++i) {
            float4 va = ea[i], vb = eb[i], vc = ec[i], xx = xr[i];
            float ax = va.x - xx.x, ay = va.y - xx.y, az = va.z - xx.z, aw = va.w - xx.w;
            float bx = vb.x - xx.x, by = vb.y - xx.y, bz = vb.z - xx.z, bw = vb.w - xx.w;
            float cx = vc.x - xx.x, cy = vc.y - xx.y, cz = vc.z - xx.z, cw = vc.w - xx.w;
            da += ax * ax + ay * ay + az * az + aw * aw;
            db += bx * bx + by * by + bz * bz + bw * bw;
            dc += cx * cx + cy * cy + cz * cz + cw * cw;
        }
        da += __shfl_xor(da, 1, 64);
        db += __shfl_xor(db, 1, 64);
        dc += __shfl_xor(dc, 1, 64);

        int idx = ia; float dm = da;
        if (db < dm || (db == dm && ib < idx)) { dm = db; idx = ib; }
        if (dc < dm || (dc == dm && ic < idx)) { dm = dc; idx = ic; }

        if (hf == 0) out[grow] = (float)idx;

        const float4* q4 = reinterpret_cast<const float4*>(emb + (size_t)idx * DIM + hf * 64);
        float4* oq = reinterpret_cast<float4*>(out + (size_t)NPTS + (size_t)grow * DIM + hf * 64);
        #pragma unroll
        for (int i = 0; i < 16; ++i) oq[i] = q4[i];

        float lsum = (hf == 0) ? dm : 0.f;   // dm = exact ||x-q||^2 for the chosen code
        #pragma unroll
        for (int o = 32; o > 0; o >>= 1) lsum += __shfl_down(lsum, o);
        if (lane == 0) red[wv] = lsum;
        __syncthreads();
        if (tid == 0) {
            float s = 0.f;
            #pragma unroll
            for (int i = 0; i < 8; ++i) s += red[i];
            bsum[blockIdx.x] = s;
        }
    }
    #undef STAGE
}

__global__ void vq_finalize512(const float* __restrict__ bsum, float* __restrict__ out) {
    __shared__ float red[8];
    int t = threadIdx.x;  // 512 threads
    float v = bsum[t];
    #pragma unroll
    for (int o = 32; o > 0; o >>= 1) v += __shfl_down(v, o);
    if ((t & 63) == 0) red[t >> 6] = v;
    __syncthreads();
    if (t == 0) {
        float s = 0.f;
        #pragma unroll
        for (int i = 0; i < 8; ++i) s += red[i];
        out[(size_t)NPTS + (size_t)NPTS * DIM] = 1.25f * s / 16777216.0f;
    }
}

// ---- fallback (round-2 proven path; eeW bias is argmax-safe) ----
__global__ void vq_ee(const float* __restrict__ emb, float* __restrict__ eeW) {
    int gid  = blockIdx.x * blockDim.x + threadIdx.x;
    int w    = gid >> 6;
    int lane = threadIdx.x & 63;
    const float* e = emb + (size_t)w * DIM;
    float a = e[lane];
    float b = e[lane + 64];
    float v = a * a + b * b;
    #pragma unroll
    for (int o = 32; o > 0; o >>= 1) v += __shfl_down(v, o);
    if (lane == 0) eeW[w] = 0.5f * v - 512.0f;
}

__global__ __launch_bounds__(256, 1) void vq_main(const float* __restrict__ x,
                                                  const float* __restrict__ emb,
                                                  const float* __restrict__ eeW,
                                                  float* __restrict__ out,
                                                  float* __restrict__ bsum) {
    const int p = blockIdx.x * 256 + threadIdx.x;
    float4 xr[32];
    const float4* xv = reinterpret_cast<const float4*>(x + (size_t)p * DIM);
    #pragma unroll
    for (int i = 0; i < 32; ++i) xr[i] = xv[i];
    float bestv = -3.4e38f; int bi = 0;
    for (int k = 0; k < KC; ++k) {
        const int ku = __builtin_amdgcn_readfirstlane(k);
        const float4* e4 = reinterpret_cast<const float4*>(emb + (size_t)ku * DIM);
        float a0 = 0.f, a1 = 0.f, a2 = 0.f, a3 = 0.f;
        #pragma unroll
        for (int i = 0; i < 32; ++i) {
            float4 ev = e4[i];
            a0 = fmaf(xr[i].x, ev.x, a0);
            a1 = fmaf(xr[i].y, ev.y, a1);
            a2 = fmaf(xr[i].z, ev.z, a2);
            a3 = fmaf(xr[i].w, ev.w, a3);
        }
        float s = ((a0 + a1) + (a2 + a3)) - eeW[ku];
        if (s > bestv) { bestv = s; bi = k; }
    }
    out[p] = (float)bi;
    const float4* q4 = reinterpret_cast<const float4*>(emb + (size_t)bi * DIM);
    float4* oq = reinterpret_cast<float4*>(out + (size_t)NPTS + (size_t)p * DIM);
    float lsum = 0.f;
    #pragma unroll
    for (int i = 0; i < 32; ++i) {
        float4 qv = q4[i];
        oq[i] = qv;
        float dx = qv.x - xr[i].x;
        float dy = qv.y - xr[i].y;
        float dz = qv.z - xr[i].z;
        float dw = qv.w - xr[i].w;
        lsum += dx * dx + dy * dy + dz * dz + dw * dw;
    }
    __shared__ float red[4];
    #pragma unroll
    for (int o = 32; o > 0; o >>= 1) lsum += __shfl_down(lsum, o);
    int lane = threadIdx.x & 63, wvl = threadIdx.x >> 6;
    if (lane == 0) red[wvl] = lsum;
    __syncthreads();
    if (threadIdx.x == 0) bsum[blockIdx.x] = (red[0] + red[1]) + (red[2] + red[3]);
}

extern "C" void kernel_launch(void* const* d_in, const int* in_sizes, int n_in,
                              void* d_out, int out_size, void* d_ws, size_t ws_size,
                              hipStream_t stream) {
    const float* x   = (const float*)d_in[0];
    const float* emb = (const float*)d_in[1];
    float* out = (float*)d_out;
    char*  ws  = (char*)d_ws;

    if (ws_size >= 268288) {
        unsigned short* wsE = (unsigned short*)ws;           // 256 KB f16 image
        float* eeW  = (float*)(ws + 262144);                 // 4 KB
        float* bsum = (float*)(ws + 266240);                 // 2 KB
        vq_prep<<<256, 256, 0, stream>>>(emb, wsE, eeW);
        vq_mfma<<<512, 512, 0, stream>>>(x, emb, wsE, eeW, out, bsum);
        vq_finalize512<<<1, 512, 0, stream>>>(bsum, out);
    } else {
        float* eeW  = (float*)ws;
        float* bsum = (float*)ws + 1024;
        vq_ee<<<256, 256, 0, stream>>>(emb, eeW);
        vq_main<<<512, 256, 0, stream>>>(x, emb, eeW, out, bsum);
        vq_finalize512<<<1, 512, 0, stream>>>(bsum, out);
    }
}

// Round 16
// 113.257 us; speedup vs baseline: 1.1475x; 1.0126x over previous
//
#include <hip/hip_runtime.h>

#define NPTS 131072
#define DIM  128
#define KC   1024

using half8 = __attribute__((ext_vector_type(8))) _Float16;
using f32x4 = __attribute__((ext_vector_type(4))) float;

static __device__ __forceinline__ unsigned umax_(unsigned a, unsigned b){ return a > b ? a : b; }
static __device__ __forceinline__ unsigned med3u(unsigned a, unsigned b, unsigned c){
    unsigned d;
    asm("v_med3_u32 %0, %1, %2, %3" : "=v"(d) : "v"(a), "v"(b), "v"(c));
    return d;
}

// ws layout (bytes):
//   [0, 262144)        f16 codebook image, 16 chunks x 16KB, FRAGMENT-MAJOR:
//                      element (code, k), code=(ch*64 + ct*16 + c), k=(kc*32 + g*8 + j)
//                      at ch*16384 + ct*4096 + kc*1024 + g*256 + c*16 + j*2
//   [262144, 266240)   eeW[1024] = 0.5*||e||^2 - 512   (chunk-contiguous)
//   [266240, 268288)   bsum[512]

// ---- prep: fragment-major f16 image + eeW, one wave per code ----
__global__ void vq_prep(const float* __restrict__ emb, unsigned short* __restrict__ wsE,
                        float* __restrict__ eeW) {
    int lane = threadIdx.x & 63, wv = threadIdx.x >> 6;
    int code = blockIdx.x * 4 + wv;                 // 256 blocks x 4 waves = 1024 codes
    const float* e = emb + (size_t)code * DIM;
    float a = e[lane], b = e[lane + 64];            // k = lane, k = lane+64

    int chunk = code >> 6, r = code & 63;
    int ct = r >> 4, c = r & 15;
    int kc = lane >> 5, g = (lane >> 3) & 3, j = lane & 7;
    size_t off = (size_t)chunk * 16384 + (size_t)(ct * 4096 + kc * 1024 + g * 256 + c * 16 + j * 2);
    _Float16 ha = (_Float16)a, hb = (_Float16)b;
    wsE[off >> 1]          = __builtin_bit_cast(unsigned short, ha);
    wsE[(off + 2048) >> 1] = __builtin_bit_cast(unsigned short, hb);

    float v = a * a + b * b;
    #pragma unroll
    for (int o = 32; o > 0; o >>= 1) v += __shfl_down(v, o);
    if (lane == 0) eeW[code] = 0.5f * v - 512.0f;
}

// ---- fused pass: 8 waves x 32 rows (shared B), counted-vmcnt 3-buf + ct-ahead PRELOAD ----
__global__ __launch_bounds__(512, 1) void vq_mfma(const float* __restrict__ x,
                                                  const float* __restrict__ emb,
                                                  const unsigned short* __restrict__ wsE,
                                                  const float* __restrict__ eeW,
                                                  float* __restrict__ out,
                                                  float* __restrict__ bsum) {
    __shared__ __attribute__((aligned(128))) char lds[3][16640];
    __shared__ int   lbest[256];
    __shared__ float red[8];
    const int tid  = threadIdx.x;
    const int lane = tid & 63, wv = tid >> 6;       // 8 waves
    const int g    = lane >> 4, c = lane & 15;
    const int blockbase = blockIdx.x * 256;

    // A fragments: x row (blockbase + wv*32 + rt*16 + c), k = kc*32 + g*8 + j
    half8 ah[2][4];
    #pragma unroll
    for (int rt = 0; rt < 2; ++rt) {
        const float* xr = x + (size_t)(blockbase + wv * 32 + rt * 16 + c) * DIM;
        #pragma unroll
        for (int kc = 0; kc < 4; ++kc) {
            const float4* p = reinterpret_cast<const float4*>(xr + kc * 32 + g * 8);
            float4 v0 = p[0], v1 = p[1];
            half8 hh;
            hh[0] = (_Float16)v0.x; hh[1] = (_Float16)v0.y;
            hh[2] = (_Float16)v0.z; hh[3] = (_Float16)v0.w;
            hh[4] = (_Float16)v1.x; hh[5] = (_Float16)v1.y;
            hh[6] = (_Float16)v1.z; hh[7] = (_Float16)v1.w;
            ah[rt][kc] = hh;
        }
    }

    unsigned m1[8], m2[8], m3[8];          // [rt*4+q] packed keys, descending
    #pragma unroll
    for (int i = 0; i < 8; ++i) { m1[i] = 0u; m2[i] = 0u; m3[i] = 0u; }

    // 3 vm-ops/wave: 2x b128 slice + duplicated 256B eeW copy (identical data, benign).
    #define STAGE(BUF, CH)                                                                   \
        do {                                                                                 \
            const char* src_ = (const char*)wsE + (size_t)(CH) * 16384 + (size_t)wv * 2048;  \
            char* dst_ = &lds[(BUF)][0] + wv * 2048;                                         \
            _Pragma("unroll")                                                                \
            for (int it = 0; it < 2; ++it) {                                                 \
                __builtin_amdgcn_global_load_lds(                                            \
                    (const __attribute__((address_space(1))) void*)(src_ + it * 1024 + lane * 16), \
                    (__attribute__((address_space(3))) void*)(dst_ + it * 1024),             \
                    16, 0, 0);                                                               \
            }                                                                                \
            __builtin_amdgcn_global_load_lds(                                                \
                (const __attribute__((address_space(1))) void*)(eeW + (size_t)(CH) * 64 + lane), \
                (__attribute__((address_space(3))) void*)(&lds[(BUF)][0] + 16384),           \
                4, 0, 0);                                                                    \
        } while (0)

    // register read-ahead: next ct's B-fragments + eec (fragment-major: base+imm offsets)
    #define PRELOAD(L_, CT_)                                                                 \
        do {                                                                                 \
            const char* Lf_ = (L_) + (size_t)(lane << 4);                                    \
            bq[0] = *reinterpret_cast<const half8*>(Lf_ + ((CT_) * 4096 + 0 * 1024));        \
            bq[1] = *reinterpret_cast<const half8*>(Lf_ + ((CT_) * 4096 + 1 * 1024));        \
            bq[2] = *reinterpret_cast<const half8*>(Lf_ + ((CT_) * 4096 + 2 * 1024));        \
            bq[3] = *reinterpret_cast<const half8*>(Lf_ + ((CT_) * 4096 + 3 * 1024));        \
            eecq  = *reinterpret_cast<const float*>((L_) + 16384 + (((CT_) * 16 + c) << 2)); \
        } while (0)

    half8 bq[4]; float eecq;

    STAGE(0, 0);
    STAGE(1, 1);

    #pragma unroll
    for (int ch = 0; ch < 16; ++ch) {
        // stage(ch) complete; stage(ch+1)'s 3 ops may stay in flight across the barrier
        if (ch < 15) { asm volatile("s_waitcnt vmcnt(3)" ::: "memory"); }
        else         { asm volatile("s_waitcnt vmcnt(0)" ::: "memory"); }
        __builtin_amdgcn_sched_barrier(0);
        __builtin_amdgcn_s_barrier();          // raw: no vmcnt drain
        __builtin_amdgcn_sched_barrier(0);
        if (ch + 2 < 16) STAGE((ch + 2) % 3, ch + 2);   // overwrites buf[(ch-1)%3], released at barrier

        const char* L = &lds[ch % 3][0];
        PRELOAD(L, 0);                          // ct0 reads (partially hidden under STAGE issue)

        #pragma unroll
        for (int ct = 0; ct < 4; ++ct) {
            half8 b0 = bq[0], b1 = bq[1], b2 = bq[2], b3 = bq[3];
            const float eec = eecq;
            if (ct < 3) PRELOAD(L, ct + 1);     // next ct's 5 LDS reads fly under the MFMAs

            f32x4 acc0 = {-eec, -eec, -eec, -eec};   // fold -eeW into C-in (one code/column)
            f32x4 acc1 = {-eec, -eec, -eec, -eec};
            __builtin_amdgcn_s_setprio(1);
            acc0 = __builtin_amdgcn_mfma_f32_16x16x32_f16(ah[0][0], b0, acc0, 0, 0, 0);
            acc1 = __builtin_amdgcn_mfma_f32_16x16x32_f16(ah[1][0], b0, acc1, 0, 0, 0);
            acc0 = __builtin_amdgcn_mfma_f32_16x16x32_f16(ah[0][1], b1, acc0, 0, 0, 0);
            acc1 = __builtin_amdgcn_mfma_f32_16x16x32_f16(ah[1][1], b1, acc1, 0, 0, 0);
            acc0 = __builtin_amdgcn_mfma_f32_16x16x32_f16(ah[0][2], b2, acc0, 0, 0, 0);
            acc1 = __builtin_amdgcn_mfma_f32_16x16x32_f16(ah[1][2], b2, acc1, 0, 0, 0);
            acc0 = __builtin_amdgcn_mfma_f32_16x16x32_f16(ah[0][3], b3, acc0, 0, 0, 0);
            acc1 = __builtin_amdgcn_mfma_f32_16x16x32_f16(ah[1][3], b3, acc1, 0, 0, 0);
            __builtin_amdgcn_s_setprio(0);

            const unsigned codeC = (unsigned)(1023 - (ch * 64 + ct * 16 + c));
            #pragma unroll
            for (int q = 0; q < 4; ++q) {
                #pragma unroll
                for (int rt = 0; rt < 2; ++rt) {
                    float sp = (rt ? acc1[q] : acc0[q]);          // > 0 (bias +512)
                    unsigned u   = __builtin_bit_cast(unsigned, sp);
                    unsigned key = (u & 0xFFFFFC00u) | codeC;     // v_and_or
                    const int i = rt * 4 + q;
                    m3[i] = med3u(m2[i], m3[i], key);             // uses old m2
                    m2[i] = med3u(m1[i], m2[i], key);
                    m1[i] = umax_(m1[i], key);
                }
            }
        }
    }

    // merge top-3 across the 16 code-lanes of each g-group; stash in LDS
    #pragma unroll
    for (int rt = 0; rt < 2; ++rt) {
        #pragma unroll
        for (int q = 0; q < 4; ++q) {
            const int i = rt * 4 + q;
            unsigned a1 = m1[i], a2 = m2[i], a3 = m3[i];
            #pragma unroll
            for (int mk = 1; mk < 16; mk <<= 1) {
                unsigned b1 = (unsigned)__shfl_xor((int)a1, mk, 64);
                unsigned b2 = (unsigned)__shfl_xor((int)a2, mk, 64);
                unsigned b3 = (unsigned)__shfl_xor((int)a3, mk, 64);
                unsigned c1 = umax_(a1, b1), t1 = (a1 < b1 ? a1 : b1);
                unsigned u1 = umax_(a2, b2), u2 = (a2 < b2 ? a2 : b2);
                unsigned c2 = umax_(t1, u1), t2 = (t1 < u1 ? t1 : u1);
                unsigned c3 = umax_(umax_(t2, u2), umax_(a3, b3));
                a1 = c1; a2 = c2; a3 = c3;
            }
            if (c == 0) {
                int lr = wv * 32 + rt * 16 + g * 4 + q;
                int i1 = 1023 - (int)(a1 & 1023u);
                int i2 = 1023 - (int)(a2 & 1023u);
                int i3 = 1023 - (int)(a3 & 1023u);
                lbest[lr] = i1 | (i2 << 10) | (i3 << 20);
            }
        }
    }
    __syncthreads();

    // ---- epilogue (r7-proven clean shape): xr preloaded, fully unrolled, 2 thr/row ----
    {
        const int lrow = tid >> 1, hf = tid & 1;        // 256 rows x 2 half-threads
        const int grow = blockbase + lrow;
        const int pk = lbest[lrow];
        const int ia = pk & 1023, ib = (pk >> 10) & 1023, ic = (pk >> 20) & 1023;

        const float4* xv4 = reinterpret_cast<const float4*>(x + (size_t)grow * DIM + hf * 64);
        float4 xr[16];
        #pragma unroll
        for (int i = 0; i < 16; ++i) xr[i] = xv4[i];

        const float4* ea = reinterpret_cast<const float4*>(emb + (size_t)ia * DIM + hf * 64);
        const float4* eb = reinterpret_cast<const float4*>(emb + (size_t)ib * DIM + hf * 64);
        const float4* ec = reinterpret_cast<const float4*>(emb + (size_t)ic * DIM + hf * 64);
        float da = 0.f, db = 0.f, dc = 0.f;
        #pragma unroll
        for (int i = 0; i < 16; ++i) {
            float4 va = ea[i], vb = eb[i], vc = ec[i], xx = xr[i];
            float ax = va.x - xx.x, ay = va.y - xx.y, az = va.z - xx.z, aw = va.w - xx.w;
            float bx = vb.x - xx.x, by = vb.y - xx.y, bz = vb.z - xx.z, bw = vb.w - xx.w;
            float cx = vc.x - xx.x, cy = vc.y - xx.y, cz = vc.z - xx.z, cw = vc.w - xx.w;
            da += ax * ax + ay * ay + az * az + aw * aw;
            db += bx * bx + by * by + bz * bz + bw * bw;
            dc += cx * cx + cy * cy + cz * cz + cw * cw;
        }
        da += __shfl_xor(da, 1, 64);
        db += __shfl_xor(db, 1, 64);
        dc += __shfl_xor(dc, 1, 64);

        int idx = ia; float dm = da;
        if (db < dm || (db == dm && ib < idx)) { dm = db; idx = ib; }
        if (dc < dm || (dc == dm && ic < idx)) { dm = dc; idx = ic; }

        if (hf == 0) out[grow] = (float)idx;

        const float4* q4 = reinterpret_cast<const float4*>(emb + (size_t)idx * DIM + hf * 64);
        float4* oq = reinterpret_cast<float4*>(out + (size_t)NPTS + (size_t)grow * DIM + hf * 64);
        #pragma unroll
        for (int i = 0; i < 16; ++i) oq[i] = q4[i];

        float lsum = (hf == 0) ? dm : 0.f;   // dm = exact ||x-q||^2 for the chosen code
        #pragma unroll
        for (int o = 32; o > 0; o >>= 1) lsum += __shfl_down(lsum, o);
        if (lane == 0) red[wv] = lsum;
        __syncthreads();
        if (tid == 0) {
            float s = 0.f;
            #pragma unroll
            for (int i = 0; i < 8; ++i) s += red[i];
            bsum[blockIdx.x] = s;
        }
    }
    #undef STAGE
    #undef PRELOAD
}

__global__ void vq_finalize512(const float* __restrict__ bsum, float* __restrict__ out) {
    __shared__ float red[8];
    int t = threadIdx.x;  // 512 threads
    float v = bsum[t];
    #pragma unroll
    for (int o = 32; o > 0; o >>= 1) v += __shfl_down(v, o);
    if ((t & 63) == 0) red[t >> 6] = v;
    __syncthreads();
    if (t == 0) {
        float s = 0.f;
        #pragma unroll
        for (int i = 0; i < 8; ++i) s += red[i];
        out[(size_t)NPTS + (size_t)NPTS * DIM] = 1.25f * s / 16777216.0f;
    }
}

// ---- fallback (round-2 proven path; eeW bias is argmax-safe) ----
__global__ void vq_ee(const float* __restrict__ emb, float* __restrict__ eeW) {
    int gid  = blockIdx.x * blockDim.x + threadIdx.x;
    int w    = gid >> 6;
    int lane = threadIdx.x & 63;
    const float* e = emb + (size_t)w * DIM;
    float a = e[lane];
    float b = e[lane + 64];
    float v = a * a + b * b;
    #pragma unroll
    for (int o = 32; o > 0; o >>= 1) v += __shfl_down(v, o);
    if (lane == 0) eeW[w] = 0.5f * v - 512.0f;
}

__global__ __launch_bounds__(256, 1) void vq_main(const float* __restrict__ x,
                                                  const float* __restrict__ emb,
                                                  const float* __restrict__ eeW,
                                                  float* __restrict__ out,
                                                  float* __restrict__ bsum) {
    const int p = blockIdx.x * 256 + threadIdx.x;
    float4 xr[32];
    const float4* xv = reinterpret_cast<const float4*>(x + (size_t)p * DIM);
    #pragma unroll
    for (int i = 0; i < 32; ++i) xr[i] = xv[i];
    float bestv = -3.4e38f; int bi = 0;
    for (int k = 0; k < KC; ++k) {
        const int ku = __builtin_amdgcn_readfirstlane(k);
        const float4* e4 = reinterpret_cast<const float4*>(emb + (size_t)ku * DIM);
        float a0 = 0.f, a1 = 0.f, a2 = 0.f, a3 = 0.f;
        #pragma unroll
        for (int i = 0; i < 32; ++i) {
            float4 ev = e4[i];
            a0 = fmaf(xr[i].x, ev.x, a0);
            a1 = fmaf(xr[i].y, ev.y, a1);
            a2 = fmaf(xr[i].z, ev.z, a2);
            a3 = fmaf(xr[i].w, ev.w, a3);
        }
        float s = ((a0 + a1) + (a2 + a3)) - eeW[ku];
        if (s > bestv) { bestv = s; bi = k; }
    }
    out[p] = (float)bi;
    const float4* q4 = reinterpret_cast<const float4*>(emb + (size_t)bi * DIM);
    float4* oq = reinterpret_cast<float4*>(out + (size_t)NPTS + (size_t)p * DIM);
    float lsum = 0.f;
    #pragma unroll
    for (int i = 0; i < 32; ++i) {
        float4 qv = q4[i];
        oq[i] = qv;
        float dx = qv.x - xr[i].x;
        float dy = qv.y - xr[i].y;
        float dz = qv.z - xr[i].z;
        float dw = qv.w - xr[i].w;
        lsum += dx * dx + dy * dy + dz * dz + dw * dw;
    }
    __shared__ float red[4];
    #pragma unroll
    for (int o = 32; o > 0; o >>= 1) lsum += __shfl_down(lsum, o);
    int lane = threadIdx.x & 63, wvl = threadIdx.x >> 6;
    if (lane == 0) red[wvl] = lsum;
    __syncthreads();
    if (threadIdx.x == 0) bsum[blockIdx.x] = (red[0] + red[1]) + (red[2] + red[3]);
}

extern "C" void kernel_launch(void* const* d_in, const int* in_sizes, int n_in,
                              void* d_out, int out_size, void* d_ws, size_t ws_size,
                              hipStream_t stream) {
    const float* x   = (const float*)d_in[0];
    const float* emb = (const float*)d_in[1];
    float* out = (float*)d_out;
    char*  ws  = (char*)d_ws;

    if (ws_size >= 268288) {
        unsigned short* wsE = (unsigned short*)ws;           // 256 KB f16 image
        float* eeW  = (float*)(ws + 262144);                 // 4 KB
        float* bsum = (float*)(ws + 266240);                 // 2 KB
        vq_prep<<<256, 256, 0, stream>>>(emb, wsE, eeW);
        vq_mfma<<<512, 512, 0, stream>>>(x, emb, wsE, eeW, out, bsum);
        vq_finalize512<<<1, 512, 0, stream>>>(bsum, out);
    } else {
        float* eeW  = (float*)ws;
        float* bsum = (float*)ws + 1024;
        vq_ee<<<256, 256, 0, stream>>>(emb, eeW);
        vq_main<<<512, 256, 0, stream>>>(x, emb, eeW, out, bsum);
        vq_finalize512<<<1, 512, 0, stream>>>(bsum, out);
    }
}